// Round 7
// baseline (170.991 us; speedup 1.0000x reference)
//
#include <hip/hip_runtime.h>
#include <hip/hip_bf16.h>

typedef __bf16 bf16;
typedef bf16 bf16x8 __attribute__((ext_vector_type(8)));
typedef bf16 bf16x4 __attribute__((ext_vector_type(4)));
typedef float f32x4 __attribute__((ext_vector_type(4)));
typedef _Float16 f16x4 __attribute__((ext_vector_type(4)));

#define SCALE_LOG2 0.06376237f   // (1/sqrt(512)) * log2(e): scores in log2 domain

// ---------------------------------------------------------------------------
// I/O is FP32 (reference dtypes); internal compute bf16 MFMA.
// Workspace: qh/kh/vT 2M bf16 each, phx 4M bf16, W*T 0.25M bf16 x3,
//            Oa/Ob 2M f32 each (s-split partial contexts), la/lb 64K f32.
// ---------------------------------------------------------------------------

// ------------- prep: LDS-tiled transpose fp32 W -> bf16 W^T
__global__ __launch_bounds__(256) void prep_kernel(
    const float* __restrict__ Wq, const float* __restrict__ Wp, const float* __restrict__ Wf,
    bf16* __restrict__ WqT, bf16* __restrict__ WpT, bf16* __restrict__ WfT)
{
  const int tid = threadIdx.x;
  __shared__ bf16 t[64][72];
  const int m = blockIdx.x >> 6;
  const int tb = blockIdx.x & 63;
  const int tr = tb >> 3, tc = tb & 7;
  const float* W = (m == 0) ? Wq : (m == 1) ? Wp : Wf;
  bf16*        O = (m == 0) ? WqT : (m == 1) ? WpT : WfT;
  const int r = tid >> 2, cg = tid & 3;
  {
    const float* src = W + (size_t)(tr * 64 + r) * 512 + tc * 64 + cg * 16;
    f32x4 a = *(const f32x4*)src, b2 = *(const f32x4*)(src + 4);
    f32x4 c = *(const f32x4*)(src + 8), d = *(const f32x4*)(src + 12);
    bf16x8 lo, hi;
#pragma unroll
    for (int j = 0; j < 4; j++) { lo[j] = (bf16)a[j]; lo[4 + j] = (bf16)b2[j]; hi[j] = (bf16)c[j]; hi[4 + j] = (bf16)d[j]; }
    *(bf16x8*)(&t[r][cg * 16])     = lo;
    *(bf16x8*)(&t[r][cg * 16 + 8]) = hi;
  }
  __syncthreads();
  bf16x8 o0, o1;
#pragma unroll
  for (int j = 0; j < 8; j++) { o0[j] = t[cg * 16 + j][r]; o1[j] = t[cg * 16 + 8 + j][r]; }
  bf16* dst = O + (size_t)(tc * 64 + r) * 512 + tr * 64 + cg * 16;
  *(bf16x8*)dst = o0;
  *(bf16x8*)(dst + 8) = o1;
}

// ------------- fused projection GEMM, OPERAND-SWAPPED, BK=64; phx zero rows fused.
// R7: vtile ALIASED into As/Bs space (dead after the final k-loop sync): LDS back
// to 36.9KB -> 3 blocks/CU (R6's separate vtile pushed it to 70.7KB -> 1-2/CU and
// likely cancelled the V-epilogue win). Prefetch + XCD swizzle kept.
__global__ __launch_bounds__(256) void proj_gemm(
    const float* __restrict__ q, const float* __restrict__ k, const float* __restrict__ v,
    const float* __restrict__ pos,
    const bf16* __restrict__ WqT, const bf16* __restrict__ WpT, const float* __restrict__ bq,
    bf16* __restrict__ qh, bf16* __restrict__ kh, bf16* __restrict__ vT, bf16* __restrict__ phx)
{
  __shared__ bf16 ABs[2 * 128 * 72];   // As | Bs (36,864 B); reused as vtile post-loop
  bf16* As = ABs;
  bf16* Bs = ABs + 128 * 72;
  bf16* vtile = ABs;                   // [m=128][n pad 132] = 16,896 elem <= 36,864
  const int tid = threadIdx.x;
  const int wave = tid >> 6, lane = tid & 63, quad = lane >> 4, ln = lane & 15;
  // bijective decode: wg = xcd + 8*(4*g2 + tn), tm = xcd + 8*g2
  const int wg = blockIdx.x;
  const int xcd = wg & 7, sidx = wg >> 3;
  const int tn = sidx & 3;
  const int tm = xcd + ((sidx >> 2) << 3);          // 0..127
  const int kind = tm >> 5;               // 0=q 1=k 2=v 3=pos
  const int rr0 = (tm & 31) * 128;
  const float* X = (kind == 0) ? q : (kind == 1) ? k : (kind == 2) ? v : pos;
  const bf16* WT = ((kind < 3) ? WqT : WpT) + (size_t)tn * 128 * 512;
  const int qn_ = (wave & 1) * 64;        // nn quadrant
  const int qr_ = (wave >> 1) * 64;       // rr quadrant
  const int srow = tid >> 2, scg = tid & 3;

  f32x4 acc[4][4] = {};   // [i: nn-sub][j: rr-sub]

  // prefetch registers for one k-tile
  f32x4  xa0[4], xa1[4];
  bf16x8 wr0[2], wr1[2];
  {
    const float* p0 = X + (size_t)(rr0 + srow) * 512 + scg * 16;
    const float* p1 = X + (size_t)(rr0 + srow + 64) * 512 + scg * 16;
#pragma unroll
    for (int u = 0; u < 4; u++) { xa0[u] = *(const f32x4*)(p0 + u * 4); xa1[u] = *(const f32x4*)(p1 + u * 4); }
    const bf16* w0 = WT + (size_t)srow * 512 + scg * 16;
    const bf16* w1 = WT + (size_t)(srow + 64) * 512 + scg * 16;
    wr0[0] = *(const bf16x8*)w0; wr0[1] = *(const bf16x8*)(w0 + 8);
    wr1[0] = *(const bf16x8*)w1; wr1[1] = *(const bf16x8*)(w1 + 8);
  }

  for (int kk = 0; kk < 8; kk++) {
    __syncthreads();   // prev compute's LDS reads done
    {
      bf16x8 lo, hi;
#pragma unroll
      for (int j = 0; j < 4; j++) { lo[j] = (bf16)xa0[0][j]; lo[4 + j] = (bf16)xa0[1][j]; hi[j] = (bf16)xa0[2][j]; hi[4 + j] = (bf16)xa0[3][j]; }
      *(bf16x8*)(As + srow * 72 + scg * 16)     = lo;
      *(bf16x8*)(As + srow * 72 + scg * 16 + 8) = hi;
#pragma unroll
      for (int j = 0; j < 4; j++) { lo[j] = (bf16)xa1[0][j]; lo[4 + j] = (bf16)xa1[1][j]; hi[j] = (bf16)xa1[2][j]; hi[4 + j] = (bf16)xa1[3][j]; }
      *(bf16x8*)(As + (srow + 64) * 72 + scg * 16)     = lo;
      *(bf16x8*)(As + (srow + 64) * 72 + scg * 16 + 8) = hi;
      *(bf16x8*)(Bs + srow * 72 + scg * 16)            = wr0[0];
      *(bf16x8*)(Bs + srow * 72 + scg * 16 + 8)        = wr0[1];
      *(bf16x8*)(Bs + (srow + 64) * 72 + scg * 16)     = wr1[0];
      *(bf16x8*)(Bs + (srow + 64) * 72 + scg * 16 + 8) = wr1[1];
    }
    __syncthreads();   // staged tile visible; vmem queue empty

    // issue next k-tile loads: in flight across the 32-MFMA compute phase
    if (kk < 7) {
      const int k0n = (kk + 1) * 64;
      const float* p0 = X + (size_t)(rr0 + srow) * 512 + k0n + scg * 16;
      const float* p1 = X + (size_t)(rr0 + srow + 64) * 512 + k0n + scg * 16;
#pragma unroll
      for (int u = 0; u < 4; u++) { xa0[u] = *(const f32x4*)(p0 + u * 4); xa1[u] = *(const f32x4*)(p1 + u * 4); }
      const bf16* w0 = WT + (size_t)srow * 512 + k0n + scg * 16;
      const bf16* w1 = WT + (size_t)(srow + 64) * 512 + k0n + scg * 16;
      wr0[0] = *(const bf16x8*)w0; wr0[1] = *(const bf16x8*)(w0 + 8);
      wr1[0] = *(const bf16x8*)w1; wr1[1] = *(const bf16x8*)(w1 + 8);
    }

#pragma unroll
    for (int ks = 0; ks < 2; ks++) {
      bf16x8 wf[4], xf[4];
#pragma unroll
      for (int i = 0; i < 4; i++) {
        wf[i] = *(const bf16x8*)(Bs + (qn_ + i * 16 + ln) * 72 + ks * 32 + quad * 8);
        xf[i] = *(const bf16x8*)(As + (qr_ + i * 16 + ln) * 72 + ks * 32 + quad * 8);
      }
#pragma unroll
      for (int i = 0; i < 4; i++)
#pragma unroll
        for (int j = 0; j < 4; j++)
          acc[i][j] = __builtin_amdgcn_mfma_f32_16x16x32_bf16(wf[i], xf[j], acc[i][j], 0, 0, 0);
    }
  }
  __syncthreads();   // all compute reads done before epilogue reuses ABs as vtile

  // epilogue: lane reg r -> nn = tn*128+qn_+16i+4quad+r (4-run), rr = rr0+qr_+16j+ln
  if (kind == 2) {
    // V: transpose via vtile [m=rr-local][n=nn-local] (aliased LDS)
#pragma unroll
    for (int i = 0; i < 4; i++) {
      const int nloc = qn_ + i * 16 + quad * 4;
      f32x4 b4 = *(const f32x4*)(bq + tn * 128 + nloc);
#pragma unroll
      for (int j = 0; j < 4; j++) {
        const int mloc = qr_ + j * 16 + ln;
        bf16x4 pk;
#pragma unroll
        for (int r = 0; r < 4; r++) pk[r] = (bf16)(acc[i][j][r] + b4[r]);
        *(bf16x4*)(vtile + mloc * 132 + nloc) = pk;
      }
    }
    __syncthreads();
    const int n = tid >> 1, mh = (tid & 1) * 64;
    const int bb2 = rr0 >> 10, tt0 = rr0 & 1023;
    bf16* vdst = vT + ((size_t)(bb2 * 16 + tn * 4 + (n >> 5)) * 32 + (n & 31)) * 1024 + tt0 + mh;
#pragma unroll
    for (int c = 0; c < 8; c++) {
      bf16x8 oc;
#pragma unroll
      for (int e = 0; e < 8; e++) oc[e] = vtile[(mh + c * 8 + e) * 132 + n];
      *(bf16x8*)(vdst + c * 8) = oc;
    }
  } else {
#pragma unroll
    for (int i = 0; i < 4; i++) {
      const int nn0 = tn * 128 + qn_ + i * 16 + quad * 4;
      const int dd0 = nn0 & 31, hh = nn0 >> 5;
      f32x4 b4 = {0.f, 0.f, 0.f, 0.f};
      if (kind < 3) b4 = *(const f32x4*)(bq + nn0);
#pragma unroll
      for (int j = 0; j < 4; j++) {
        const int rr = rr0 + qr_ + j * 16 + ln;
        const int bb = rr >> 10, tt = rr & 1023;
        const size_t base = (size_t)(bb * 16 + hh);
        bf16x4 pk;
#pragma unroll
        for (int r = 0; r < 4; r++) pk[r] = (bf16)(acc[i][j][r] + b4[r]);
        if (kind == 0)      *(bf16x4*)(qh + (base * 1024 + tt) * 32 + dd0) = pk;
        else if (kind == 1) *(bf16x4*)(kh + (base * 1024 + tt) * 32 + dd0) = pk;
        else {
          *(bf16x4*)(phx + (base * 2048 + tt) * 32 + dd0) = pk;
          if (tt <= 1021) *(bf16x4*)(phx + (base * 2048 + tt + 1025) * 32 + dd0) = pk;
          if (tt == 1023) {   // fused zero rows 1024 & 2047 (unique writer per (bb,hh,dd0))
            bf16x4 zz = {};
            *(bf16x4*)(phx + (base * 2048 + 1024) * 32 + dd0) = zz;
            *(bf16x4*)(phx + (base * 2048 + 2047) * 32 + dd0) = zz;
          }
        }
      }
    }
  }
}

// ------------- fused flash attention, log2-domain, STATIC SOFTMAX (no running max).
// R7: DOUBLE-BUFFERED staged tiles -> ONE barrier per si (was 2). With dbuf,
// "prev reads done before overwrite" is free (other buffer), so barrier #1 is
// gone; the single barrier publishes the ds_writes (its vmcnt drain is vacuous —
// loads already consumed by the writes). Prefetch issued post-barrier, in flight
// across the full compute phase. Evidence: R6 showed loop time ~ instruction+sync
// count (funnel shift: −24 insts -> −740cy/block-si); one barrier ≈ −150-250cy.
// LDS 59.9KB -> 2 blocks/CU (kernel proven occupancy-insensitive, R0-R2).
__global__ __launch_bounds__(256, 4) void attn_kernel(
    const bf16* __restrict__ qh, const bf16* __restrict__ kh,
    const bf16* __restrict__ vT, const bf16* __restrict__ phx,
    const float* __restrict__ u_bias, const float* __restrict__ v_bias,
    float* __restrict__ Oa, float* __restrict__ Ob,
    float* __restrict__ la, float* __restrict__ lb)
{
  __shared__ bf16     kst[2][64 * 40];   // kh tile  [s=64][d=32 pad 40]  x2 = 10,240 B
  __shared__ bf16     phs[2][128 * 40];  // phx tile [j=128][d=32 pad 40] x2 = 20,480 B
  __shared__ bf16     vst[2][32 * 72];   // vT tile  [d=32][s=64 pad 72]  x2 =  9,216 B
  __shared__ _Float16 fs[4 * 16 * 84];   // per-wave F band [t=16][j=80 pad 84] 10,752 B
  __shared__ bf16     pb[4 * 16 * 72];   // per-wave P [t=16][s=64 pad 72]       9,216 B

  const int tid = threadIdx.x;
  const int wave = tid >> 6, lane = tid & 63, quad = lane >> 4, ln = lane & 15;
  const int wg = blockIdx.x;
  const int bh = wg & 63;                   // XCD-friendly: same head -> same wg%8
  const int rest = wg >> 6;                 // 0..31
  const int tq = rest & 15, sc = rest >> 4; // t-tile, s-chunk
  const int h = bh & 15, b = bh >> 4;
  const int t0 = tq * 64;
  const bf16* qh_h  = qh  + (size_t)bh * 1024 * 32;
  const bf16* kh_h  = kh  + (size_t)bh * 1024 * 32;
  const bf16* vT_h  = vT  + (size_t)bh * 32 * 1024;
  const bf16* phx_h = phx + (size_t)bh * 2048 * 32;

  _Float16* fsw = fs + wave * 16 * 84;
  bf16*     pbw = pb + wave * 16 * 72;

  // staging decomposition (block-cooperative)
  const int sr4 = tid >> 2, sc4 = tid & 3;   // kst/phs: 16B chunks of 64B rows
  const int sr8 = tid >> 3, sc8 = tid & 7;   // vst: 16B chunks of 128B rows

  // funnel-shift constants for the combine gather (per-lane)
  const int Ab  = quad * 4 + ((15 - ln) & ~3);   // aligned window start (mult of 4)
  const int msh = ((15 - ln) & 3) * 16;          // bit shift within window

  // B-operand fragments (B[n=t][k=d]), pre-scaled by S2, resident all si.
  bf16x8 qu, qva, qvn;
  {
    const int t = t0 + wave * 16 + ln;
    bf16x8 q0 = *(const bf16x8*)(qh_h + (size_t)t * 32 + quad * 8);
    bf16x8 q1 = *(const bf16x8*)(qh_h + (size_t)(t + 1) * 32 + quad * 8);  // t=1023 tail: never used
    const float* ubp = u_bias + h * 32 + quad * 8;
    const float* vbp = v_bias + h * 32 + quad * 8;
#pragma unroll
    for (int j = 0; j < 8; j++) {
      qu[j]  = (bf16)(((float)q0[j] + ubp[j]) * SCALE_LOG2);
      qva[j] = (bf16)(((float)q0[j] + vbp[j]) * SCALE_LOG2);
      qvn[j] = (bf16)(((float)q1[j] + vbp[j]) * SCALE_LOG2);
    }
  }

  f32x4 O0 = {0.f, 0.f, 0.f, 0.f}, O1 = {0.f, 0.f, 0.f, 0.f};
  float l_lane = 0.0f;    // per-lane partial denominator (t=ln, this quad's 16 s per si)
  const f32x4 zf = {0.f, 0.f, 0.f, 0.f};

  const int si0 = sc * 8;

  // prologue: issue first tile loads into registers
  bf16x8 g0, g1, g2, g3;
  {
    const int s0p = si0 * 64, jbp = s0p - t0 + 960;
    g0 = *(const bf16x8*)(kh_h  + (size_t)(s0p + sr4) * 32 + sc4 * 8);
    g1 = *(const bf16x8*)(phx_h + (size_t)(jbp + sr4) * 32 + sc4 * 8);
    g2 = *(const bf16x8*)(phx_h + (size_t)(jbp + 64 + sr4) * 32 + sc4 * 8);
    g3 = *(const bf16x8*)(vT_h  + (size_t)sr8 * 1024 + s0p + sc8 * 8);
  }

#pragma unroll 2
  for (int si = si0; si < si0 + 8; si++) {
    const int buf = si & 1;                            // si0 even -> starts at 0
    const int s0 = si * 64;
    const int jbase = s0 - t0 + 960;                   // phx window base, in [0, 1920]
    const int jb0 = jbase + (3 - wave) * 16;           // this wave's F window start
    bf16* kc = kst[buf];
    bf16* pc = phs[buf];
    bf16* vc = vst[buf];

    // ---- write prefetched tile to LDS buf (prev buffer's readers unaffected)
    *(bf16x8*)(kc + sr4 * 40 + sc4 * 8)        = g0;
    *(bf16x8*)(pc + sr4 * 40 + sc4 * 8)        = g1;
    *(bf16x8*)(pc + (64 + sr4) * 40 + sc4 * 8) = g2;
    *(bf16x8*)(vc + sr8 * 72 + sc8 * 8)        = g3;

    // ---- single barrier: writes visible; vmcnt drain vacuous (loads consumed)
    __syncthreads();

    // ---- issue NEXT tile's loads: in flight across the whole compute phase
    if (si != si0 + 7) {
      const int s0n = s0 + 64, jbn = jbase + 64;
      g0 = *(const bf16x8*)(kh_h  + (size_t)(s0n + sr4) * 32 + sc4 * 8);
      g1 = *(const bf16x8*)(phx_h + (size_t)(jbn + sr4) * 32 + sc4 * 8);
      g2 = *(const bf16x8*)(phx_h + (size_t)(jbn + 64 + sr4) * 32 + sc4 * 8);
      g3 = *(const bf16x8*)(vT_h  + (size_t)sr8 * 1024 + s0n + sc8 * 8);
    }

    // ---- F band: 5 subtiles, A = phs rows (LDS), B = qva/qvn (16-aligned threshold)
#pragma unroll
    for (int i = 0; i < 5; i++) {
      const int row = (3 - wave + i) * 16 + ln;        // = (jb0 + i*16 + ln) - jbase
      bf16x8 pbf = *(const bf16x8*)(pc + row * 40 + quad * 8);
      bf16x8 bsel = (jb0 + i * 16 >= 1024) ? qvn : qva;
      f32x4 f = __builtin_amdgcn_mfma_f32_16x16x32_bf16(pbf, bsel, zf, 0, 0, 0);
      f16x4 fh;
#pragma unroll
      for (int r = 0; r < 4; r++) fh[r] = (_Float16)f[r];
      *(f16x4*)(fsw + ln * 84 + i * 16 + quad * 4) = fh;   // [t=ln][j-cols], 8B aligned
    }

    // ---- content: S^T, A = kst rows (LDS), B = qu (regs)
    f32x4 c[4];
#pragma unroll
    for (int cs = 0; cs < 4; cs++) {
      bf16x8 kbf = *(const bf16x8*)(kc + (cs * 16 + ln) * 40 + quad * 8);
      c[cs] = __builtin_amdgcn_mfma_f32_16x16x32_bf16(kbf, qu, zf, 0, 0, 0);
    }

    // ---- combine + exp2 + accumulate l + stage P (funnel-shift F gather)
    const _Float16* rowp = fsw + ln * 84;
#pragma unroll
    for (int cs = 0; cs < 4; cs++) {
      const uint64_t v0 = *(const uint64_t*)(rowp + cs * 16 + Ab);      // hw Ab..Ab+3
      const uint64_t v1 = *(const uint64_t*)(rowp + cs * 16 + Ab + 4);  // hw Ab+4..Ab+7
      union { uint64_t u; f16x4 v; } W;
      W.u = (v0 >> msh) | ((v1 << 1) << (63 - msh));   // hw[m..m+3]; branch-free at m=0
      bf16x4 pk;
#pragma unroll
      for (int r = 0; r < 4; r++) {
        const float p = __builtin_amdgcn_exp2f(c[cs][r] + (float)W.v[r]);
        l_lane += p;
        pk[r] = (bf16)p;
      }
      *(bf16x4*)(pbw + ln * 72 + cs * 16 + quad * 4) = pk;   // P[t=ln][s]
    }

    // ---- PV: A = P[t][s] (LDS, same wave), B = vst rows (LDS)
#pragma unroll
    for (int kb = 0; kb < 2; kb++) {
      bf16x8 a  = *(const bf16x8*)(pbw + ln * 72 + kb * 32 + quad * 8);
      bf16x8 b0 = *(const bf16x8*)(vc + ln * 72 + kb * 32 + quad * 8);
      bf16x8 b1 = *(const bf16x8*)(vc + (16 + ln) * 72 + kb * 32 + quad * 8);
      O0 = __builtin_amdgcn_mfma_f32_16x16x32_bf16(a, b0, O0, 0, 0, 0);
      O1 = __builtin_amdgcn_mfma_f32_16x16x32_bf16(a, b1, O1, 0, 0, 0);
    }
  }

  // ---- epilogue: reduce l across quads, store UNNORMALIZED partial O (f32) + l
  l_lane += __shfl_xor(l_lane, 16);
  l_lane += __shfl_xor(l_lane, 32);   // now l for row t=ln, this chunk

  float* Op = sc ? Ob : Oa;
  float* lp = sc ? lb : la;
#pragma unroll
  for (int r = 0; r < 4; r++) {
    const int t = t0 + wave * 16 + quad * 4 + r;
    const size_t o = ((size_t)(b * 1024 + t)) * 512 + h * 32;
    Op[o + ln]      = O0[r];
    Op[o + 16 + ln] = O1[r];
  }
  if (lane < 16) lp[(size_t)bh * 1024 + t0 + wave * 16 + lane] = l_lane;
}

// ------------- output projection: combine s-split partials, normalize, @ Wf + bf.
// R7: 32x128 tiles -> 512 blocks = 2 blocks/CU (was 256 = exactly 1/CU, the
// canonical under-occupancy config). Prefetch + XCD swizzle kept.
__global__ __launch_bounds__(256) void out_gemm(
    const float* __restrict__ Oa, const float* __restrict__ Ob,
    const float* __restrict__ la, const float* __restrict__ lb,
    const bf16* __restrict__ WfT, const float* __restrict__ bfv,
    float* __restrict__ out)
{
  __shared__ bf16 As[32 * 40];      //  2,560 B
  __shared__ bf16 Bs[128 * 40];     // 10,240 B
  __shared__ float linv[16 * 32];   // [h][row-in-tile] 2 KB
  const int tid = threadIdx.x;
  const int wave = tid >> 6, lane = tid & 63, quad = lane >> 4, ln = lane & 15;
  // bijective decode: wg = xcd + 8*(4*g2 + tn), tm = xcd + 8*g2  (512 blocks)
  const int wg = blockIdx.x;
  const int xcd = wg & 7, sidx = wg >> 3;
  const int tn = sidx & 3;
  const int tm = xcd + ((sidx >> 2) << 3);    // 0..127
  const int rr0 = tm * 32;
  const bf16* WT = WfT + (size_t)tn * 128 * 512;
  const int qm = (wave & 1) * 16, qn = (wave >> 1) * 64;
  const int srow = tid >> 2, scg = tid & 3;      // Bs staging (64 rows x 32 k, x2)
  const int srow8 = tid >> 3, scg8 = tid & 7;    // As staging (32 rows x 8 f32x4)

  // prefetch regs + prologue load (kk=0); overlaps the linv phase
  f32x4 a0, c0;
  bf16x8 b0r, b1r;
  {
    a0 = *(const f32x4*)(Oa + (size_t)(rr0 + srow8) * 512 + scg8 * 4);
    c0 = *(const f32x4*)(Ob + (size_t)(rr0 + srow8) * 512 + scg8 * 4);
    b0r = *(const bf16x8*)(WT + (size_t)srow * 512 + scg * 8);
    b1r = *(const bf16x8*)(WT + (size_t)(srow + 64) * 512 + scg * 8);
  }

  // precompute 1/(la+lb) for the 32 rows x 16 heads of this tile
  for (int e = tid; e < 512; e += 256) {
    const int hh = e >> 5, r = e & 31;
    const int row = rr0 + r;
    const int b_ = row >> 10, t_ = row & 1023;
    const size_t li = ((size_t)(b_ * 16 + hh)) * 1024 + t_;
    linv[e] = 1.0f / (la[li] + lb[li]);
  }

  f32x4 acc[4] = {};
  for (int kk = 0; kk < 16; kk++) {
    __syncthreads();   // prev compute reads done (kk=0: also fences linv writes)
    {
      const float s = linv[kk * 32 + srow8];   // head = kk for cols [k0, k0+32)
      bf16x4 t4;
#pragma unroll
      for (int j = 0; j < 4; j++) t4[j] = (bf16)((a0[j] + c0[j]) * s);
      *(bf16x4*)(As + srow8 * 40 + scg8 * 4)      = t4;
      *(bf16x8*)(Bs + srow * 40 + scg * 8)        = b0r;
      *(bf16x8*)(Bs + (srow + 64) * 40 + scg * 8) = b1r;
    }
    __syncthreads();

    if (kk < 15) {
      const int k0n = (kk + 1) * 32;
      a0 = *(const f32x4*)(Oa + (size_t)(rr0 + srow8) * 512 + k0n + scg8 * 4);
      c0 = *(const f32x4*)(Ob + (size_t)(rr0 + srow8) * 512 + k0n + scg8 * 4);
      b0r = *(const bf16x8*)(WT + (size_t)srow * 512 + k0n + scg * 8);
      b1r = *(const bf16x8*)(WT + (size_t)(srow + 64) * 512 + k0n + scg * 8);
    }

    bf16x8 af, bfm[4];
    af = *(const bf16x8*)(As + (qm + ln) * 40 + quad * 8);
#pragma unroll
    for (int j = 0; j < 4; j++)
      bfm[j] = *(const bf16x8*)(Bs + (qn + j * 16 + ln) * 40 + quad * 8);
#pragma unroll
    for (int j = 0; j < 4; j++)
      acc[j] = __builtin_amdgcn_mfma_f32_16x16x32_bf16(af, bfm[j], acc[j], 0, 0, 0);
  }

#pragma unroll
  for (int j = 0; j < 4; j++) {
    const int nn = tn * 128 + qn + j * 16 + ln;
    const float bias = bfv[nn];
#pragma unroll
    for (int r = 0; r < 4; r++) {
      const int rr = rr0 + qm + quad * 4 + r;
      out[(size_t)rr * 512 + nn] = acc[j][r] + bias;
    }
  }
}

// ---------------------------------------------------------------------------
extern "C" void kernel_launch(void* const* d_in, const int* in_sizes, int n_in,
                              void* d_out, int out_size, void* d_ws, size_t ws_size,
                              hipStream_t stream) {
  const float* q   = (const float*)d_in[0];
  const float* k   = (const float*)d_in[1];
  const float* v   = (const float*)d_in[2];
  const float* pe  = (const float*)d_in[3];
  const float* Wq  = (const float*)d_in[4];
  const float* bq  = (const float*)d_in[5];
  const float* Wp  = (const float*)d_in[6];
  const float* Wf  = (const float*)d_in[7];
  const float* bfv = (const float*)d_in[8];
  const float* ub  = (const float*)d_in[9];
  const float* vb  = (const float*)d_in[10];

  bf16* ws  = (bf16*)d_ws;
  bf16* qh  = ws;                  // qh first: t+1 tail reads land in kh (finite, unused)
  bf16* kh  = qh + 2097152;
  bf16* vT  = kh + 2097152;
  bf16* phx = vT + 2097152;
  bf16* WqT = phx + 4194304;
  bf16* WpT = WqT + 262144;
  bf16* WfT = WpT + 262144;
  float* Oa = (float*)(WfT + 262144);   // byte offset 22,544,384 (16B-aligned)
  float* Ob = Oa + 2097152;
  float* la = Ob + 2097152;
  float* lb = la + 65536;

  prep_kernel<<<192, 256, 0, stream>>>(Wq, Wp, Wf, WqT, WpT, WfT);
  proj_gemm<<<512, 256, 0, stream>>>(q, k, v, pe, WqT, WpT, bq, qh, kh, vT, phx);
  attn_kernel<<<2048, 256, 0, stream>>>(qh, kh, vT, phx, ub, vb, Oa, Ob, la, lb);
  out_gemm<<<512, 256, 0, stream>>>(Oa, Ob, la, lb, WfT, bfv, (float*)d_out);
}

// Round 8
// 158.911 us; speedup vs baseline: 1.0760x; 1.0760x over previous
//
#include <hip/hip_runtime.h>
#include <hip/hip_bf16.h>

typedef __bf16 bf16;
typedef bf16 bf16x8 __attribute__((ext_vector_type(8)));
typedef bf16 bf16x4 __attribute__((ext_vector_type(4)));
typedef float f32x4 __attribute__((ext_vector_type(4)));
typedef _Float16 f16x4 __attribute__((ext_vector_type(4)));

#define SCALE_LOG2 0.06376237f   // (1/sqrt(512)) * log2(e): scores in log2 domain

// ---------------------------------------------------------------------------
// I/O is FP32 (reference dtypes); internal compute bf16 MFMA.
// Workspace (bf16): qh/kh/vT 2M each, phx 4M, W*T 0.25M x3, ctx 2M.
// R8: s-split removed (it was an occupancy fix for a disproven theory; its
// residual cost was +25MB of f32 partial traffic through attn+out).
// ---------------------------------------------------------------------------

// ------------- prep: LDS-tiled transpose fp32 W -> bf16 W^T
__global__ __launch_bounds__(256) void prep_kernel(
    const float* __restrict__ Wq, const float* __restrict__ Wp, const float* __restrict__ Wf,
    bf16* __restrict__ WqT, bf16* __restrict__ WpT, bf16* __restrict__ WfT)
{
  const int tid = threadIdx.x;
  __shared__ bf16 t[64][72];
  const int m = blockIdx.x >> 6;
  const int tb = blockIdx.x & 63;
  const int tr = tb >> 3, tc = tb & 7;
  const float* W = (m == 0) ? Wq : (m == 1) ? Wp : Wf;
  bf16*        O = (m == 0) ? WqT : (m == 1) ? WpT : WfT;
  const int r = tid >> 2, cg = tid & 3;
  {
    const float* src = W + (size_t)(tr * 64 + r) * 512 + tc * 64 + cg * 16;
    f32x4 a = *(const f32x4*)src, b2 = *(const f32x4*)(src + 4);
    f32x4 c = *(const f32x4*)(src + 8), d = *(const f32x4*)(src + 12);
    bf16x8 lo, hi;
#pragma unroll
    for (int j = 0; j < 4; j++) { lo[j] = (bf16)a[j]; lo[4 + j] = (bf16)b2[j]; hi[j] = (bf16)c[j]; hi[4 + j] = (bf16)d[j]; }
    *(bf16x8*)(&t[r][cg * 16])     = lo;
    *(bf16x8*)(&t[r][cg * 16 + 8]) = hi;
  }
  __syncthreads();
  bf16x8 o0, o1;
#pragma unroll
  for (int j = 0; j < 8; j++) { o0[j] = t[cg * 16 + j][r]; o1[j] = t[cg * 16 + 8 + j][r]; }
  bf16* dst = O + (size_t)(tc * 64 + r) * 512 + tr * 64 + cg * 16;
  *(bf16x8*)dst = o0;
  *(bf16x8*)(dst + 8) = o1;
}

// ------------- fused projection GEMM, OPERAND-SWAPPED, BK=64; phx zero rows fused.
// vtile aliased into As/Bs (dead after final k-loop sync); prefetch + XCD swizzle.
__global__ __launch_bounds__(256) void proj_gemm(
    const float* __restrict__ q, const float* __restrict__ k, const float* __restrict__ v,
    const float* __restrict__ pos,
    const bf16* __restrict__ WqT, const bf16* __restrict__ WpT, const float* __restrict__ bq,
    bf16* __restrict__ qh, bf16* __restrict__ kh, bf16* __restrict__ vT, bf16* __restrict__ phx)
{
  __shared__ bf16 ABs[2 * 128 * 72];   // As | Bs (36,864 B); reused as vtile post-loop
  bf16* As = ABs;
  bf16* Bs = ABs + 128 * 72;
  bf16* vtile = ABs;                   // [m=128][n pad 132] = 16,896 elem <= 36,864
  const int tid = threadIdx.x;
  const int wave = tid >> 6, lane = tid & 63, quad = lane >> 4, ln = lane & 15;
  // bijective decode: wg = xcd + 8*(4*g2 + tn), tm = xcd + 8*g2
  const int wg = blockIdx.x;
  const int xcd = wg & 7, sidx = wg >> 3;
  const int tn = sidx & 3;
  const int tm = xcd + ((sidx >> 2) << 3);          // 0..127
  const int kind = tm >> 5;               // 0=q 1=k 2=v 3=pos
  const int rr0 = (tm & 31) * 128;
  const float* X = (kind == 0) ? q : (kind == 1) ? k : (kind == 2) ? v : pos;
  const bf16* WT = ((kind < 3) ? WqT : WpT) + (size_t)tn * 128 * 512;
  const int qn_ = (wave & 1) * 64;        // nn quadrant
  const int qr_ = (wave >> 1) * 64;       // rr quadrant
  const int srow = tid >> 2, scg = tid & 3;

  f32x4 acc[4][4] = {};   // [i: nn-sub][j: rr-sub]

  // prefetch registers for one k-tile
  f32x4  xa0[4], xa1[4];
  bf16x8 wr0[2], wr1[2];
  {
    const float* p0 = X + (size_t)(rr0 + srow) * 512 + scg * 16;
    const float* p1 = X + (size_t)(rr0 + srow + 64) * 512 + scg * 16;
#pragma unroll
    for (int u = 0; u < 4; u++) { xa0[u] = *(const f32x4*)(p0 + u * 4); xa1[u] = *(const f32x4*)(p1 + u * 4); }
    const bf16* w0 = WT + (size_t)srow * 512 + scg * 16;
    const bf16* w1 = WT + (size_t)(srow + 64) * 512 + scg * 16;
    wr0[0] = *(const bf16x8*)w0; wr0[1] = *(const bf16x8*)(w0 + 8);
    wr1[0] = *(const bf16x8*)w1; wr1[1] = *(const bf16x8*)(w1 + 8);
  }

  for (int kk = 0; kk < 8; kk++) {
    __syncthreads();   // prev compute's LDS reads done
    {
      bf16x8 lo, hi;
#pragma unroll
      for (int j = 0; j < 4; j++) { lo[j] = (bf16)xa0[0][j]; lo[4 + j] = (bf16)xa0[1][j]; hi[j] = (bf16)xa0[2][j]; hi[4 + j] = (bf16)xa0[3][j]; }
      *(bf16x8*)(As + srow * 72 + scg * 16)     = lo;
      *(bf16x8*)(As + srow * 72 + scg * 16 + 8) = hi;
#pragma unroll
      for (int j = 0; j < 4; j++) { lo[j] = (bf16)xa1[0][j]; lo[4 + j] = (bf16)xa1[1][j]; hi[j] = (bf16)xa1[2][j]; hi[4 + j] = (bf16)xa1[3][j]; }
      *(bf16x8*)(As + (srow + 64) * 72 + scg * 16)     = lo;
      *(bf16x8*)(As + (srow + 64) * 72 + scg * 16 + 8) = hi;
      *(bf16x8*)(Bs + srow * 72 + scg * 16)            = wr0[0];
      *(bf16x8*)(Bs + srow * 72 + scg * 16 + 8)        = wr0[1];
      *(bf16x8*)(Bs + (srow + 64) * 72 + scg * 16)     = wr1[0];
      *(bf16x8*)(Bs + (srow + 64) * 72 + scg * 16 + 8) = wr1[1];
    }
    __syncthreads();   // staged tile visible; vmem queue empty

    // issue next k-tile loads: in flight across the 32-MFMA compute phase
    if (kk < 7) {
      const int k0n = (kk + 1) * 64;
      const float* p0 = X + (size_t)(rr0 + srow) * 512 + k0n + scg * 16;
      const float* p1 = X + (size_t)(rr0 + srow + 64) * 512 + k0n + scg * 16;
#pragma unroll
      for (int u = 0; u < 4; u++) { xa0[u] = *(const f32x4*)(p0 + u * 4); xa1[u] = *(const f32x4*)(p1 + u * 4); }
      const bf16* w0 = WT + (size_t)srow * 512 + k0n + scg * 16;
      const bf16* w1 = WT + (size_t)(srow + 64) * 512 + k0n + scg * 16;
      wr0[0] = *(const bf16x8*)w0; wr0[1] = *(const bf16x8*)(w0 + 8);
      wr1[0] = *(const bf16x8*)w1; wr1[1] = *(const bf16x8*)(w1 + 8);
    }

#pragma unroll
    for (int ks = 0; ks < 2; ks++) {
      bf16x8 wf[4], xf[4];
#pragma unroll
      for (int i = 0; i < 4; i++) {
        wf[i] = *(const bf16x8*)(Bs + (qn_ + i * 16 + ln) * 72 + ks * 32 + quad * 8);
        xf[i] = *(const bf16x8*)(As + (qr_ + i * 16 + ln) * 72 + ks * 32 + quad * 8);
      }
#pragma unroll
      for (int i = 0; i < 4; i++)
#pragma unroll
        for (int j = 0; j < 4; j++)
          acc[i][j] = __builtin_amdgcn_mfma_f32_16x16x32_bf16(wf[i], xf[j], acc[i][j], 0, 0, 0);
    }
  }
  __syncthreads();   // all compute reads done before epilogue reuses ABs as vtile

  // epilogue: lane reg r -> nn = tn*128+qn_+16i+4quad+r (4-run), rr = rr0+qr_+16j+ln
  if (kind == 2) {
    // V: transpose via vtile [m=rr-local][n=nn-local] (aliased LDS)
#pragma unroll
    for (int i = 0; i < 4; i++) {
      const int nloc = qn_ + i * 16 + quad * 4;
      f32x4 b4 = *(const f32x4*)(bq + tn * 128 + nloc);
#pragma unroll
      for (int j = 0; j < 4; j++) {
        const int mloc = qr_ + j * 16 + ln;
        bf16x4 pk;
#pragma unroll
        for (int r = 0; r < 4; r++) pk[r] = (bf16)(acc[i][j][r] + b4[r]);
        *(bf16x4*)(vtile + mloc * 132 + nloc) = pk;
      }
    }
    __syncthreads();
    const int n = tid >> 1, mh = (tid & 1) * 64;
    const int bb2 = rr0 >> 10, tt0 = rr0 & 1023;
    bf16* vdst = vT + ((size_t)(bb2 * 16 + tn * 4 + (n >> 5)) * 32 + (n & 31)) * 1024 + tt0 + mh;
#pragma unroll
    for (int c = 0; c < 8; c++) {
      bf16x8 oc;
#pragma unroll
      for (int e = 0; e < 8; e++) oc[e] = vtile[(mh + c * 8 + e) * 132 + n];
      *(bf16x8*)(vdst + c * 8) = oc;
    }
  } else {
#pragma unroll
    for (int i = 0; i < 4; i++) {
      const int nn0 = tn * 128 + qn_ + i * 16 + quad * 4;
      const int dd0 = nn0 & 31, hh = nn0 >> 5;
      f32x4 b4 = {0.f, 0.f, 0.f, 0.f};
      if (kind < 3) b4 = *(const f32x4*)(bq + nn0);
#pragma unroll
      for (int j = 0; j < 4; j++) {
        const int rr = rr0 + qr_ + j * 16 + ln;
        const int bb = rr >> 10, tt = rr & 1023;
        const size_t base = (size_t)(bb * 16 + hh);
        bf16x4 pk;
#pragma unroll
        for (int r = 0; r < 4; r++) pk[r] = (bf16)(acc[i][j][r] + b4[r]);
        if (kind == 0)      *(bf16x4*)(qh + (base * 1024 + tt) * 32 + dd0) = pk;
        else if (kind == 1) *(bf16x4*)(kh + (base * 1024 + tt) * 32 + dd0) = pk;
        else {
          *(bf16x4*)(phx + (base * 2048 + tt) * 32 + dd0) = pk;
          if (tt <= 1021) *(bf16x4*)(phx + (base * 2048 + tt + 1025) * 32 + dd0) = pk;
          if (tt == 1023) {   // fused zero rows 1024 & 2047 (unique writer per (bb,hh,dd0))
            bf16x4 zz = {};
            *(bf16x4*)(phx + (base * 2048 + 1024) * 32 + dd0) = zz;
            *(bf16x4*)(phx + (base * 2048 + 2047) * 32 + dd0) = zz;
          }
        }
      }
    }
  }
}

// ------------- fused flash attention, log2-domain, STATIC SOFTMAX (no running max).
// R8: R6-exact inner loop (single-buffer, 2 barriers, post-barrier prefetch,
// funnel-shift combine — the proven 46us config; R7's dbuf cost VGPR 56->88 and
// occupancy 34->18%, reverted). De-split: 1024 blocks x 16 si, normalize
// in-kernel, write bf16 ctx (saves 25MB of f32 partial traffic downstream).
__global__ __launch_bounds__(256, 4) void attn_kernel(
    const bf16* __restrict__ qh, const bf16* __restrict__ kh,
    const bf16* __restrict__ vT, const bf16* __restrict__ phx,
    const float* __restrict__ u_bias, const float* __restrict__ v_bias,
    bf16* __restrict__ ctx)
{
  __shared__ bf16     kst[64 * 40];     // kh tile  [s=64][d=32 pad 40]   5,120 B
  __shared__ bf16     phs[128 * 40];    // phx tile [j=128][d=32 pad 40] 10,240 B
  __shared__ bf16     vst[32 * 72];     // vT tile  [d=32][s=64 pad 72]   4,608 B
  __shared__ _Float16 fs[4 * 16 * 84];  // per-wave F band [t=16][j=80 pad 84] 10,752 B
  __shared__ bf16     pb[4 * 16 * 72];  // per-wave P [t=16][s=64 pad 72]       9,216 B

  const int tid = threadIdx.x;
  const int wave = tid >> 6, lane = tid & 63, quad = lane >> 4, ln = lane & 15;
  const int wg = blockIdx.x;
  const int bh = wg & 63;                   // XCD-friendly: same head -> same wg%8
  const int tq = wg >> 6;                   // 0..15
  const int h = bh & 15, b = bh >> 4;
  const int t0 = tq * 64;
  const bf16* qh_h  = qh  + (size_t)bh * 1024 * 32;
  const bf16* kh_h  = kh  + (size_t)bh * 1024 * 32;
  const bf16* vT_h  = vT  + (size_t)bh * 32 * 1024;
  const bf16* phx_h = phx + (size_t)bh * 2048 * 32;

  _Float16* fsw = fs + wave * 16 * 84;
  bf16*     pbw = pb + wave * 16 * 72;

  // staging decomposition (block-cooperative)
  const int sr4 = tid >> 2, sc4 = tid & 3;   // kst/phs: 16B chunks of 64B rows
  const int sr8 = tid >> 3, sc8 = tid & 7;   // vst: 16B chunks of 128B rows

  // funnel-shift constants for the combine gather (per-lane)
  const int Ab  = quad * 4 + ((15 - ln) & ~3);   // aligned window start (mult of 4)
  const int msh = ((15 - ln) & 3) * 16;          // bit shift within window

  // B-operand fragments (B[n=t][k=d]), pre-scaled by S2, resident all si.
  bf16x8 qu, qva, qvn;
  {
    const int t = t0 + wave * 16 + ln;
    bf16x8 q0 = *(const bf16x8*)(qh_h + (size_t)t * 32 + quad * 8);
    bf16x8 q1 = *(const bf16x8*)(qh_h + (size_t)(t + 1) * 32 + quad * 8);  // t=1023 tail: never used
    const float* ubp = u_bias + h * 32 + quad * 8;
    const float* vbp = v_bias + h * 32 + quad * 8;
#pragma unroll
    for (int j = 0; j < 8; j++) {
      qu[j]  = (bf16)(((float)q0[j] + ubp[j]) * SCALE_LOG2);
      qva[j] = (bf16)(((float)q0[j] + vbp[j]) * SCALE_LOG2);
      qvn[j] = (bf16)(((float)q1[j] + vbp[j]) * SCALE_LOG2);
    }
  }

  f32x4 O0 = {0.f, 0.f, 0.f, 0.f}, O1 = {0.f, 0.f, 0.f, 0.f};
  float l_lane = 0.0f;    // per-lane partial denominator (t=ln, this quad's 16 s per si)
  const f32x4 zf = {0.f, 0.f, 0.f, 0.f};

  // prologue: issue first tile loads into registers
  bf16x8 g0, g1, g2, g3;
  {
    const int jbp = -t0 + 960;
    g0 = *(const bf16x8*)(kh_h  + (size_t)sr4 * 32 + sc4 * 8);
    g1 = *(const bf16x8*)(phx_h + (size_t)(jbp + sr4) * 32 + sc4 * 8);
    g2 = *(const bf16x8*)(phx_h + (size_t)(jbp + 64 + sr4) * 32 + sc4 * 8);
    g3 = *(const bf16x8*)(vT_h  + (size_t)sr8 * 1024 + sc8 * 8);
  }

  for (int si = 0; si < 16; si++) {
    const int s0 = si * 64;
    const int jbase = s0 - t0 + 960;                   // phx window base, in [0, 1920]
    const int jb0 = jbase + (3 - wave) * 16;           // this wave's F window start

    // ---- barrier #1: prev si's LDS reads done; drains prefetch (needed now anyway)
    __syncthreads();

    // ---- write prefetched tile to LDS
    *(bf16x8*)(kst + sr4 * 40 + sc4 * 8)        = g0;
    *(bf16x8*)(phs + sr4 * 40 + sc4 * 8)        = g1;
    *(bf16x8*)(phs + (64 + sr4) * 40 + sc4 * 8) = g2;
    *(bf16x8*)(vst + sr8 * 72 + sc8 * 8)        = g3;

    // ---- barrier #2: writes visible; vmem queue empty -> vmcnt(0) vacuous
    __syncthreads();

    // ---- issue NEXT tile's loads now: in flight across the whole compute phase
    if (si != 15) {
      const int s0n = s0 + 64, jbn = jbase + 64;
      g0 = *(const bf16x8*)(kh_h  + (size_t)(s0n + sr4) * 32 + sc4 * 8);
      g1 = *(const bf16x8*)(phx_h + (size_t)(jbn + sr4) * 32 + sc4 * 8);
      g2 = *(const bf16x8*)(phx_h + (size_t)(jbn + 64 + sr4) * 32 + sc4 * 8);
      g3 = *(const bf16x8*)(vT_h  + (size_t)sr8 * 1024 + s0n + sc8 * 8);
    }

    // ---- F band: 5 subtiles, A = phs rows (LDS), B = qva/qvn (16-aligned threshold)
#pragma unroll
    for (int i = 0; i < 5; i++) {
      const int row = (3 - wave + i) * 16 + ln;        // = (jb0 + i*16 + ln) - jbase
      bf16x8 pbf = *(const bf16x8*)(phs + row * 40 + quad * 8);
      bf16x8 bsel = (jb0 + i * 16 >= 1024) ? qvn : qva;
      f32x4 f = __builtin_amdgcn_mfma_f32_16x16x32_bf16(pbf, bsel, zf, 0, 0, 0);
      f16x4 fh;
#pragma unroll
      for (int r = 0; r < 4; r++) fh[r] = (_Float16)f[r];
      *(f16x4*)(fsw + ln * 84 + i * 16 + quad * 4) = fh;   // [t=ln][j-cols], 8B aligned
    }

    // ---- content: S^T, A = kst rows (LDS), B = qu (regs)
    f32x4 c[4];
#pragma unroll
    for (int cs = 0; cs < 4; cs++) {
      bf16x8 kbf = *(const bf16x8*)(kst + (cs * 16 + ln) * 40 + quad * 8);
      c[cs] = __builtin_amdgcn_mfma_f32_16x16x32_bf16(kbf, qu, zf, 0, 0, 0);
    }

    // ---- combine + exp2 + accumulate l + stage P (funnel-shift F gather)
    const _Float16* rowp = fsw + ln * 84;
#pragma unroll
    for (int cs = 0; cs < 4; cs++) {
      const uint64_t v0 = *(const uint64_t*)(rowp + cs * 16 + Ab);      // hw Ab..Ab+3
      const uint64_t v1 = *(const uint64_t*)(rowp + cs * 16 + Ab + 4);  // hw Ab+4..Ab+7
      union { uint64_t u; f16x4 v; } W;
      W.u = (v0 >> msh) | ((v1 << 1) << (63 - msh));   // hw[m..m+3]; branch-free at m=0
      bf16x4 pk;
#pragma unroll
      for (int r = 0; r < 4; r++) {
        const float p = __builtin_amdgcn_exp2f(c[cs][r] + (float)W.v[r]);
        l_lane += p;
        pk[r] = (bf16)p;
      }
      *(bf16x4*)(pbw + ln * 72 + cs * 16 + quad * 4) = pk;   // P[t=ln][s]
    }

    // ---- PV: A = P[t][s] (LDS, same wave), B = vst rows (LDS)
#pragma unroll
    for (int kb = 0; kb < 2; kb++) {
      bf16x8 a  = *(const bf16x8*)(pbw + ln * 72 + kb * 32 + quad * 8);
      bf16x8 b0 = *(const bf16x8*)(vst + ln * 72 + kb * 32 + quad * 8);
      bf16x8 b1 = *(const bf16x8*)(vst + (16 + ln) * 72 + kb * 32 + quad * 8);
      O0 = __builtin_amdgcn_mfma_f32_16x16x32_bf16(a, b0, O0, 0, 0, 0);
      O1 = __builtin_amdgcn_mfma_f32_16x16x32_bf16(a, b1, O1, 0, 0, 0);
    }
  }

  // ---- epilogue: reduce l across quads (once), normalize, store bf16 ctx
  l_lane += __shfl_xor(l_lane, 16);
  l_lane += __shfl_xor(l_lane, 32);
#pragma unroll
  for (int r = 0; r < 4; r++) {
    const float lr = __shfl(l_lane, quad * 4 + r);   // l for t-row quad*4+r
    const float inv = 1.0f / lr;
    const int t = t0 + wave * 16 + quad * 4 + r;
    const size_t o = ((size_t)(b * 1024 + t)) * 512 + h * 32;
    ctx[o + ln]      = (bf16)(O0[r] * inv);
    ctx[o + 16 + ln] = (bf16)(O1[r] * inv);
  }
}

// ------------- output projection: ctx @ Wf + bf -> out (fp32).
// R8: reads bf16 ctx directly (no partial combine/normalize). 32x128 tiles,
// 512 blocks = 2/CU; prefetch + XCD swizzle kept.
__global__ __launch_bounds__(256) void out_gemm(
    const bf16* __restrict__ ctx, const bf16* __restrict__ WfT,
    const float* __restrict__ bfv, float* __restrict__ out)
{
  __shared__ bf16 As[32 * 40];      //  2,560 B
  __shared__ bf16 Bs[128 * 40];     // 10,240 B
  const int tid = threadIdx.x;
  const int wave = tid >> 6, lane = tid & 63, quad = lane >> 4, ln = lane & 15;
  // bijective decode: wg = xcd + 8*(4*g2 + tn), tm = xcd + 8*g2  (512 blocks)
  const int wg = blockIdx.x;
  const int xcd = wg & 7, sidx = wg >> 3;
  const int tn = sidx & 3;
  const int tm = xcd + ((sidx >> 2) << 3);    // 0..127
  const int rr0 = tm * 32;
  const bf16* WT = WfT + (size_t)tn * 128 * 512;
  const int qm = (wave & 1) * 16, qn = (wave >> 1) * 64;
  const int srow = tid >> 2, scg = tid & 3;      // Bs staging (64 rows x 32 k, x2)
  const int srow8 = tid >> 3, scg8 = tid & 7;    // As staging (32 rows x 8 x bf16x4)

  // prefetch regs + prologue load (kk=0)
  bf16x4 a4;
  bf16x8 b0r, b1r;
  {
    a4  = *(const bf16x4*)(ctx + (size_t)(rr0 + srow8) * 512 + scg8 * 4);
    b0r = *(const bf16x8*)(WT + (size_t)srow * 512 + scg * 8);
    b1r = *(const bf16x8*)(WT + (size_t)(srow + 64) * 512 + scg * 8);
  }

  f32x4 acc[4] = {};
  for (int kk = 0; kk < 16; kk++) {
    __syncthreads();   // prev compute reads done (kk=0: vacuous)
    *(bf16x4*)(As + srow8 * 40 + scg8 * 4)      = a4;
    *(bf16x8*)(Bs + srow * 40 + scg * 8)        = b0r;
    *(bf16x8*)(Bs + (srow + 64) * 40 + scg * 8) = b1r;
    __syncthreads();

    if (kk < 15) {
      const int k0n = (kk + 1) * 32;
      a4  = *(const bf16x4*)(ctx + (size_t)(rr0 + srow8) * 512 + k0n + scg8 * 4);
      b0r = *(const bf16x8*)(WT + (size_t)srow * 512 + k0n + scg * 8);
      b1r = *(const bf16x8*)(WT + (size_t)(srow + 64) * 512 + k0n + scg * 8);
    }

    bf16x8 af, bfm[4];
    af = *(const bf16x8*)(As + (qm + ln) * 40 + quad * 8);
#pragma unroll
    for (int j = 0; j < 4; j++)
      bfm[j] = *(const bf16x8*)(Bs + (qn + j * 16 + ln) * 40 + quad * 8);
#pragma unroll
    for (int j = 0; j < 4; j++)
      acc[j] = __builtin_amdgcn_mfma_f32_16x16x32_bf16(af, bfm[j], acc[j], 0, 0, 0);
  }

#pragma unroll
  for (int j = 0; j < 4; j++) {
    const int nn = tn * 128 + qn + j * 16 + ln;
    const float bias = bfv[nn];
#pragma unroll
    for (int r = 0; r < 4; r++) {
      const int rr = rr0 + qm + quad * 4 + r;
      out[(size_t)rr * 512 + nn] = acc[j][r] + bias;
    }
  }
}

// ---------------------------------------------------------------------------
extern "C" void kernel_launch(void* const* d_in, const int* in_sizes, int n_in,
                              void* d_out, int out_size, void* d_ws, size_t ws_size,
                              hipStream_t stream) {
  const float* q   = (const float*)d_in[0];
  const float* k   = (const float*)d_in[1];
  const float* v   = (const float*)d_in[2];
  const float* pe  = (const float*)d_in[3];
  const float* Wq  = (const float*)d_in[4];
  const float* bq  = (const float*)d_in[5];
  const float* Wp  = (const float*)d_in[6];
  const float* Wf  = (const float*)d_in[7];
  const float* bfv = (const float*)d_in[8];
  const float* ub  = (const float*)d_in[9];
  const float* vb  = (const float*)d_in[10];

  bf16* ws  = (bf16*)d_ws;
  bf16* qh  = ws;                  // qh first: t+1 tail reads land in kh (finite, unused)
  bf16* kh  = qh + 2097152;
  bf16* vT  = kh + 2097152;
  bf16* phx = vT + 2097152;
  bf16* WqT = phx + 4194304;
  bf16* WpT = WqT + 262144;
  bf16* WfT = WpT + 262144;
  bf16* ctx = WfT + 262144;

  prep_kernel<<<192, 256, 0, stream>>>(Wq, Wp, Wf, WqT, WpT, WfT);
  proj_gemm<<<512, 256, 0, stream>>>(q, k, v, pe, WqT, WpT, bq, qh, kh, vT, phx);
  attn_kernel<<<1024, 256, 0, stream>>>(qh, kh, vT, phx, ub, vb, ctx);
  out_gemm<<<512, 256, 0, stream>>>(ctx, WfT, bfv, (float*)d_out);
}

// Round 9
// 157.914 us; speedup vs baseline: 1.0828x; 1.0063x over previous
//
#include <hip/hip_runtime.h>
#include <hip/hip_bf16.h>

typedef __bf16 bf16;
typedef bf16 bf16x8 __attribute__((ext_vector_type(8)));
typedef bf16 bf16x4 __attribute__((ext_vector_type(4)));
typedef float f32x4 __attribute__((ext_vector_type(4)));
typedef _Float16 f16x4 __attribute__((ext_vector_type(4)));

#define SCALE_LOG2 0.06376237f   // (1/sqrt(512)) * log2(e): scores in log2 domain

// ---------------------------------------------------------------------------
// I/O is FP32 (reference dtypes); internal compute bf16 MFMA.
// Workspace (bf16): qh/kh/vT 2M each, phx 4M, W*T 0.25M x3, ctx 2M.
// ---------------------------------------------------------------------------

// ------------- prep: LDS-tiled transpose fp32 W -> bf16 W^T
__global__ __launch_bounds__(256) void prep_kernel(
    const float* __restrict__ Wq, const float* __restrict__ Wp, const float* __restrict__ Wf,
    bf16* __restrict__ WqT, bf16* __restrict__ WpT, bf16* __restrict__ WfT)
{
  const int tid = threadIdx.x;
  __shared__ bf16 t[64][72];
  const int m = blockIdx.x >> 6;
  const int tb = blockIdx.x & 63;
  const int tr = tb >> 3, tc = tb & 7;
  const float* W = (m == 0) ? Wq : (m == 1) ? Wp : Wf;
  bf16*        O = (m == 0) ? WqT : (m == 1) ? WpT : WfT;
  const int r = tid >> 2, cg = tid & 3;
  {
    const float* src = W + (size_t)(tr * 64 + r) * 512 + tc * 64 + cg * 16;
    f32x4 a = *(const f32x4*)src, b2 = *(const f32x4*)(src + 4);
    f32x4 c = *(const f32x4*)(src + 8), d = *(const f32x4*)(src + 12);
    bf16x8 lo, hi;
#pragma unroll
    for (int j = 0; j < 4; j++) { lo[j] = (bf16)a[j]; lo[4 + j] = (bf16)b2[j]; hi[j] = (bf16)c[j]; hi[4 + j] = (bf16)d[j]; }
    *(bf16x8*)(&t[r][cg * 16])     = lo;
    *(bf16x8*)(&t[r][cg * 16 + 8]) = hi;
  }
  __syncthreads();
  bf16x8 o0, o1;
#pragma unroll
  for (int j = 0; j < 8; j++) { o0[j] = t[cg * 16 + j][r]; o1[j] = t[cg * 16 + 8 + j][r]; }
  bf16* dst = O + (size_t)(tc * 64 + r) * 512 + tr * 64 + cg * 16;
  *(bf16x8*)dst = o0;
  *(bf16x8*)(dst + 8) = o1;
}

// ------------- fused projection GEMM, OPERAND-SWAPPED, BK=64; phx zero rows fused.
// vtile aliased into As/Bs (dead after final k-loop sync); prefetch + XCD swizzle.
__global__ __launch_bounds__(256) void proj_gemm(
    const float* __restrict__ q, const float* __restrict__ k, const float* __restrict__ v,
    const float* __restrict__ pos,
    const bf16* __restrict__ WqT, const bf16* __restrict__ WpT, const float* __restrict__ bq,
    bf16* __restrict__ qh, bf16* __restrict__ kh, bf16* __restrict__ vT, bf16* __restrict__ phx)
{
  __shared__ bf16 ABs[2 * 128 * 72];   // As | Bs (36,864 B); reused as vtile post-loop
  bf16* As = ABs;
  bf16* Bs = ABs + 128 * 72;
  bf16* vtile = ABs;                   // [m=128][n pad 132] = 16,896 elem <= 36,864
  const int tid = threadIdx.x;
  const int wave = tid >> 6, lane = tid & 63, quad = lane >> 4, ln = lane & 15;
  // bijective decode: wg = xcd + 8*(4*g2 + tn), tm = xcd + 8*g2
  const int wg = blockIdx.x;
  const int xcd = wg & 7, sidx = wg >> 3;
  const int tn = sidx & 3;
  const int tm = xcd + ((sidx >> 2) << 3);          // 0..127
  const int kind = tm >> 5;               // 0=q 1=k 2=v 3=pos
  const int rr0 = (tm & 31) * 128;
  const float* X = (kind == 0) ? q : (kind == 1) ? k : (kind == 2) ? v : pos;
  const bf16* WT = ((kind < 3) ? WqT : WpT) + (size_t)tn * 128 * 512;
  const int qn_ = (wave & 1) * 64;        // nn quadrant
  const int qr_ = (wave >> 1) * 64;       // rr quadrant
  const int srow = tid >> 2, scg = tid & 3;

  f32x4 acc[4][4] = {};   // [i: nn-sub][j: rr-sub]

  // prefetch registers for one k-tile
  f32x4  xa0[4], xa1[4];
  bf16x8 wr0[2], wr1[2];
  {
    const float* p0 = X + (size_t)(rr0 + srow) * 512 + scg * 16;
    const float* p1 = X + (size_t)(rr0 + srow + 64) * 512 + scg * 16;
#pragma unroll
    for (int u = 0; u < 4; u++) { xa0[u] = *(const f32x4*)(p0 + u * 4); xa1[u] = *(const f32x4*)(p1 + u * 4); }
    const bf16* w0 = WT + (size_t)srow * 512 + scg * 16;
    const bf16* w1 = WT + (size_t)(srow + 64) * 512 + scg * 16;
    wr0[0] = *(const bf16x8*)w0; wr0[1] = *(const bf16x8*)(w0 + 8);
    wr1[0] = *(const bf16x8*)w1; wr1[1] = *(const bf16x8*)(w1 + 8);
  }

  for (int kk = 0; kk < 8; kk++) {
    __syncthreads();   // prev compute's LDS reads done
    {
      bf16x8 lo, hi;
#pragma unroll
      for (int j = 0; j < 4; j++) { lo[j] = (bf16)xa0[0][j]; lo[4 + j] = (bf16)xa0[1][j]; hi[j] = (bf16)xa0[2][j]; hi[4 + j] = (bf16)xa0[3][j]; }
      *(bf16x8*)(As + srow * 72 + scg * 16)     = lo;
      *(bf16x8*)(As + srow * 72 + scg * 16 + 8) = hi;
#pragma unroll
      for (int j = 0; j < 4; j++) { lo[j] = (bf16)xa1[0][j]; lo[4 + j] = (bf16)xa1[1][j]; hi[j] = (bf16)xa1[2][j]; hi[4 + j] = (bf16)xa1[3][j]; }
      *(bf16x8*)(As + (srow + 64) * 72 + scg * 16)     = lo;
      *(bf16x8*)(As + (srow + 64) * 72 + scg * 16 + 8) = hi;
      *(bf16x8*)(Bs + srow * 72 + scg * 16)            = wr0[0];
      *(bf16x8*)(Bs + srow * 72 + scg * 16 + 8)        = wr0[1];
      *(bf16x8*)(Bs + (srow + 64) * 72 + scg * 16)     = wr1[0];
      *(bf16x8*)(Bs + (srow + 64) * 72 + scg * 16 + 8) = wr1[1];
    }
    __syncthreads();   // staged tile visible; vmem queue empty

    // issue next k-tile loads: in flight across the 32-MFMA compute phase
    if (kk < 7) {
      const int k0n = (kk + 1) * 64;
      const float* p0 = X + (size_t)(rr0 + srow) * 512 + k0n + scg * 16;
      const float* p1 = X + (size_t)(rr0 + srow + 64) * 512 + k0n + scg * 16;
#pragma unroll
      for (int u = 0; u < 4; u++) { xa0[u] = *(const f32x4*)(p0 + u * 4); xa1[u] = *(const f32x4*)(p1 + u * 4); }
      const bf16* w0 = WT + (size_t)srow * 512 + k0n + scg * 16;
      const bf16* w1 = WT + (size_t)(srow + 64) * 512 + k0n + scg * 16;
      wr0[0] = *(const bf16x8*)w0; wr0[1] = *(const bf16x8*)(w0 + 8);
      wr1[0] = *(const bf16x8*)w1; wr1[1] = *(const bf16x8*)(w1 + 8);
    }

#pragma unroll
    for (int ks = 0; ks < 2; ks++) {
      bf16x8 wf[4], xf[4];
#pragma unroll
      for (int i = 0; i < 4; i++) {
        wf[i] = *(const bf16x8*)(Bs + (qn_ + i * 16 + ln) * 72 + ks * 32 + quad * 8);
        xf[i] = *(const bf16x8*)(As + (qr_ + i * 16 + ln) * 72 + ks * 32 + quad * 8);
      }
#pragma unroll
      for (int i = 0; i < 4; i++)
#pragma unroll
        for (int j = 0; j < 4; j++)
          acc[i][j] = __builtin_amdgcn_mfma_f32_16x16x32_bf16(wf[i], xf[j], acc[i][j], 0, 0, 0);
    }
  }
  __syncthreads();   // all compute reads done before epilogue reuses ABs as vtile

  // epilogue: lane reg r -> nn = tn*128+qn_+16i+4quad+r (4-run), rr = rr0+qr_+16j+ln
  if (kind == 2) {
    // V: transpose via vtile [m=rr-local][n=nn-local] (aliased LDS)
#pragma unroll
    for (int i = 0; i < 4; i++) {
      const int nloc = qn_ + i * 16 + quad * 4;
      f32x4 b4 = *(const f32x4*)(bq + tn * 128 + nloc);
#pragma unroll
      for (int j = 0; j < 4; j++) {
        const int mloc = qr_ + j * 16 + ln;
        bf16x4 pk;
#pragma unroll
        for (int r = 0; r < 4; r++) pk[r] = (bf16)(acc[i][j][r] + b4[r]);
        *(bf16x4*)(vtile + mloc * 132 + nloc) = pk;
      }
    }
    __syncthreads();
    const int n = tid >> 1, mh = (tid & 1) * 64;
    const int bb2 = rr0 >> 10, tt0 = rr0 & 1023;
    bf16* vdst = vT + ((size_t)(bb2 * 16 + tn * 4 + (n >> 5)) * 32 + (n & 31)) * 1024 + tt0 + mh;
#pragma unroll
    for (int c = 0; c < 8; c++) {
      bf16x8 oc;
#pragma unroll
      for (int e = 0; e < 8; e++) oc[e] = vtile[(mh + c * 8 + e) * 132 + n];
      *(bf16x8*)(vdst + c * 8) = oc;
    }
  } else {
#pragma unroll
    for (int i = 0; i < 4; i++) {
      const int nn0 = tn * 128 + qn_ + i * 16 + quad * 4;
      const int dd0 = nn0 & 31, hh = nn0 >> 5;
      f32x4 b4 = {0.f, 0.f, 0.f, 0.f};
      if (kind < 3) b4 = *(const f32x4*)(bq + nn0);
#pragma unroll
      for (int j = 0; j < 4; j++) {
        const int rr = rr0 + qr_ + j * 16 + ln;
        const int bb = rr >> 10, tt = rr & 1023;
        const size_t base = (size_t)(bb * 16 + hh);
        bf16x4 pk;
#pragma unroll
        for (int r = 0; r < 4; r++) pk[r] = (bf16)(acc[i][j][r] + b4[r]);
        if (kind == 0)      *(bf16x4*)(qh + (base * 1024 + tt) * 32 + dd0) = pk;
        else if (kind == 1) *(bf16x4*)(kh + (base * 1024 + tt) * 32 + dd0) = pk;
        else {
          *(bf16x4*)(phx + (base * 2048 + tt) * 32 + dd0) = pk;
          if (tt <= 1021) *(bf16x4*)(phx + (base * 2048 + tt + 1025) * 32 + dd0) = pk;
          if (tt == 1023) {   // fused zero rows 1024 & 2047 (unique writer per (bb,hh,dd0))
            bf16x4 zz = {};
            *(bf16x4*)(phx + (base * 2048 + 1024) * 32 + dd0) = zz;
            *(bf16x4*)(phx + (base * 2048 + 2047) * 32 + dd0) = zz;
          }
        }
      }
    }
  }
}

// ------------- fused flash attention, log2-domain, STATIC SOFTMAX (no running max).
// R9: LDS-op diet (36 -> 24 ops/thread-si on the proven bottleneck pipe).
// kh/phx A-operand reads go DIRECT from global: content rows (cs*16+ln) are
// wave-uniform (4 waves hit the same 1KB-coalesced lines -> L1 dedup), F-band
// rows overlap 2.5x across waves. Only vT stays staged (direct form would be
// 2KB-stride uncoalesced — the R2 disaster). vst double-buffered -> ONE barrier
// per si at tiny LDS cost: 29.2KB total -> 4 blocks/CU (occupancy UP, unlike
// R7's 60KB dbuf). Funnel-shift combine kept (R6's proven -20us).
__global__ __launch_bounds__(256, 4) void attn_kernel(
    const bf16* __restrict__ qh, const bf16* __restrict__ kh,
    const bf16* __restrict__ vT, const bf16* __restrict__ phx,
    const float* __restrict__ u_bias, const float* __restrict__ v_bias,
    bf16* __restrict__ ctx)
{
  __shared__ bf16     vst[2][32 * 72];  // vT tile [d=32][s=64 pad 72] x2 = 9,216 B
  __shared__ _Float16 fs[4 * 16 * 84];  // per-wave F band [t=16][j=80 pad 84] 10,752 B
  __shared__ bf16     pb[4 * 16 * 72];  // per-wave P [t=16][s=64 pad 72]       9,216 B

  const int tid = threadIdx.x;
  const int wave = tid >> 6, lane = tid & 63, quad = lane >> 4, ln = lane & 15;
  const int wg = blockIdx.x;
  const int bh = wg & 63;                   // XCD-friendly: same head -> same wg%8
  const int tq = wg >> 6;                   // 0..15
  const int h = bh & 15, b = bh >> 4;
  const int t0 = tq * 64;
  const bf16* qh_h  = qh  + (size_t)bh * 1024 * 32;
  const bf16* kh_h  = kh  + (size_t)bh * 1024 * 32;
  const bf16* vT_h  = vT  + (size_t)bh * 32 * 1024;
  const bf16* phx_h = phx + (size_t)bh * 2048 * 32;

  _Float16* fsw = fs + wave * 16 * 84;
  bf16*     pbw = pb + wave * 16 * 72;

  // vst staging decomposition (block-cooperative)
  const int sr8 = tid >> 3, sc8 = tid & 7;   // vst: 16B chunks of 128B rows

  // funnel-shift constants for the combine gather (per-lane)
  const int Ab  = quad * 4 + ((15 - ln) & ~3);   // aligned window start (mult of 4)
  const int msh = ((15 - ln) & 3) * 16;          // bit shift within window

  // B-operand fragments (B[n=t][k=d]), pre-scaled by S2, resident all si.
  bf16x8 qu, qva, qvn;
  {
    const int t = t0 + wave * 16 + ln;
    bf16x8 q0 = *(const bf16x8*)(qh_h + (size_t)t * 32 + quad * 8);
    bf16x8 q1 = *(const bf16x8*)(qh_h + (size_t)(t + 1) * 32 + quad * 8);  // t=1023 tail: never used
    const float* ubp = u_bias + h * 32 + quad * 8;
    const float* vbp = v_bias + h * 32 + quad * 8;
#pragma unroll
    for (int j = 0; j < 8; j++) {
      qu[j]  = (bf16)(((float)q0[j] + ubp[j]) * SCALE_LOG2);
      qva[j] = (bf16)(((float)q0[j] + vbp[j]) * SCALE_LOG2);
      qvn[j] = (bf16)(((float)q1[j] + vbp[j]) * SCALE_LOG2);
    }
  }

  f32x4 O0 = {0.f, 0.f, 0.f, 0.f}, O1 = {0.f, 0.f, 0.f, 0.f};
  float l_lane = 0.0f;    // per-lane partial denominator (t=ln, this quad's 16 s per si)
  const f32x4 zf = {0.f, 0.f, 0.f, 0.f};

  // prologue: first V tile into registers
  bf16x8 g3 = *(const bf16x8*)(vT_h + (size_t)sr8 * 1024 + sc8 * 8);

  for (int si = 0; si < 16; si++) {
    const int s0 = si * 64;
    const int jbase = s0 - t0 + 960;                   // phx window base, in [0, 1920]
    const int jb0 = jbase + (3 - wave) * 16;           // this wave's F window start
    bf16* vc = vst[si & 1];

    // ---- write this si's V tile (other buffer's readers unaffected)
    *(bf16x8*)(vc + sr8 * 72 + sc8 * 8) = g3;

    // ---- single barrier: publishes vc; si-2's reads of vc proven complete
    // (they precede si-1's barrier, which precedes this write)
    __syncthreads();

    // ---- prefetch next V tile: in flight across the whole compute phase
    if (si != 15)
      g3 = *(const bf16x8*)(vT_h + (size_t)sr8 * 1024 + s0 + 64 + sc8 * 8);

    // ---- F band: 5 subtiles, A = phx rows DIRECT (1KB-coalesced wave loads,
    //      rows overlap 2.5x across waves -> L1-served), B = qva/qvn
#pragma unroll
    for (int i = 0; i < 5; i++) {
      bf16x8 pbf = *(const bf16x8*)(phx_h + (size_t)(jb0 + i * 16 + ln) * 32 + quad * 8);
      bf16x8 bsel = (jb0 + i * 16 >= 1024) ? qvn : qva;
      f32x4 f = __builtin_amdgcn_mfma_f32_16x16x32_bf16(pbf, bsel, zf, 0, 0, 0);
      f16x4 fh;
#pragma unroll
      for (int r = 0; r < 4; r++) fh[r] = (_Float16)f[r];
      *(f16x4*)(fsw + ln * 84 + i * 16 + quad * 4) = fh;   // [t=ln][j-cols], 8B aligned
    }

    // ---- content: S^T, A = kh rows DIRECT (wave-uniform across the 4 waves
    //      -> same lines, L1 dedup), B = qu (regs)
    f32x4 c[4];
#pragma unroll
    for (int cs = 0; cs < 4; cs++) {
      bf16x8 kbf = *(const bf16x8*)(kh_h + (size_t)(s0 + cs * 16 + ln) * 32 + quad * 8);
      c[cs] = __builtin_amdgcn_mfma_f32_16x16x32_bf16(kbf, qu, zf, 0, 0, 0);
    }

    // ---- combine + exp2 + accumulate l + stage P (funnel-shift F gather)
    const _Float16* rowp = fsw + ln * 84;
#pragma unroll
    for (int cs = 0; cs < 4; cs++) {
      const uint64_t v0 = *(const uint64_t*)(rowp + cs * 16 + Ab);      // hw Ab..Ab+3
      const uint64_t v1 = *(const uint64_t*)(rowp + cs * 16 + Ab + 4);  // hw Ab+4..Ab+7
      union { uint64_t u; f16x4 v; } W;
      W.u = (v0 >> msh) | ((v1 << 1) << (63 - msh));   // hw[m..m+3]; branch-free at m=0
      bf16x4 pk;
#pragma unroll
      for (int r = 0; r < 4; r++) {
        const float p = __builtin_amdgcn_exp2f(c[cs][r] + (float)W.v[r]);
        l_lane += p;
        pk[r] = (bf16)p;
      }
      *(bf16x4*)(pbw + ln * 72 + cs * 16 + quad * 4) = pk;   // P[t=ln][s]
    }

    // ---- PV: A = P[t][s] (LDS, same wave), B = vst rows (LDS, staged)
#pragma unroll
    for (int kb = 0; kb < 2; kb++) {
      bf16x8 a  = *(const bf16x8*)(pbw + ln * 72 + kb * 32 + quad * 8);
      bf16x8 b0 = *(const bf16x8*)(vc + ln * 72 + kb * 32 + quad * 8);
      bf16x8 b1 = *(const bf16x8*)(vc + (16 + ln) * 72 + kb * 32 + quad * 8);
      O0 = __builtin_amdgcn_mfma_f32_16x16x32_bf16(a, b0, O0, 0, 0, 0);
      O1 = __builtin_amdgcn_mfma_f32_16x16x32_bf16(a, b1, O1, 0, 0, 0);
    }
  }

  // ---- epilogue: reduce l across quads (once), normalize, store bf16 ctx
  l_lane += __shfl_xor(l_lane, 16);
  l_lane += __shfl_xor(l_lane, 32);
#pragma unroll
  for (int r = 0; r < 4; r++) {
    const float lr = __shfl(l_lane, quad * 4 + r);   // l for t-row quad*4+r
    const float inv = 1.0f / lr;
    const int t = t0 + wave * 16 + quad * 4 + r;
    const size_t o = ((size_t)(b * 1024 + t)) * 512 + h * 32;
    ctx[o + ln]      = (bf16)(O0[r] * inv);
    ctx[o + 16 + ln] = (bf16)(O1[r] * inv);
  }
}

// ------------- output projection: ctx @ Wf + bf -> out (fp32).
// 32x128 tiles, 512 blocks = 2/CU; prefetch + XCD swizzle kept.
__global__ __launch_bounds__(256) void out_gemm(
    const bf16* __restrict__ ctx, const bf16* __restrict__ WfT,
    const float* __restrict__ bfv, float* __restrict__ out)
{
  __shared__ bf16 As[32 * 40];      //  2,560 B
  __shared__ bf16 Bs[128 * 40];     // 10,240 B
  const int tid = threadIdx.x;
  const int wave = tid >> 6, lane = tid & 63, quad = lane >> 4, ln = lane & 15;
  // bijective decode: wg = xcd + 8*(4*g2 + tn), tm = xcd + 8*g2  (512 blocks)
  const int wg = blockIdx.x;
  const int xcd = wg & 7, sidx = wg >> 3;
  const int tn = sidx & 3;
  const int tm = xcd + ((sidx >> 2) << 3);    // 0..127
  const int rr0 = tm * 32;
  const bf16* WT = WfT + (size_t)tn * 128 * 512;
  const int qm = (wave & 1) * 16, qn = (wave >> 1) * 64;
  const int srow = tid >> 2, scg = tid & 3;      // Bs staging (64 rows x 32 k, x2)
  const int srow8 = tid >> 3, scg8 = tid & 7;    // As staging (32 rows x 8 x bf16x4)

  // prefetch regs + prologue load (kk=0)
  bf16x4 a4;
  bf16x8 b0r, b1r;
  {
    a4  = *(const bf16x4*)(ctx + (size_t)(rr0 + srow8) * 512 + scg8 * 4);
    b0r = *(const bf16x8*)(WT + (size_t)srow * 512 + scg * 8);
    b1r = *(const bf16x8*)(WT + (size_t)(srow + 64) * 512 + scg * 8);
  }

  f32x4 acc[4] = {};
  for (int kk = 0; kk < 16; kk++) {
    __syncthreads();   // prev compute reads done (kk=0: vacuous)
    *(bf16x4*)(As + srow8 * 40 + scg8 * 4)      = a4;
    *(bf16x8*)(Bs + srow * 40 + scg * 8)        = b0r;
    *(bf16x8*)(Bs + (srow + 64) * 40 + scg * 8) = b1r;
    __syncthreads();

    if (kk < 15) {
      const int k0n = (kk + 1) * 32;
      a4  = *(const bf16x4*)(ctx + (size_t)(rr0 + srow8) * 512 + k0n + scg8 * 4);
      b0r = *(const bf16x8*)(WT + (size_t)srow * 512 + k0n + scg * 8);
      b1r = *(const bf16x8*)(WT + (size_t)(srow + 64) * 512 + k0n + scg * 8);
    }

    bf16x8 af, bfm[4];
    af = *(const bf16x8*)(As + (qm + ln) * 40 + quad * 8);
#pragma unroll
    for (int j = 0; j < 4; j++)
      bfm[j] = *(const bf16x8*)(Bs + (qn + j * 16 + ln) * 40 + quad * 8);
#pragma unroll
    for (int j = 0; j < 4; j++)
      acc[j] = __builtin_amdgcn_mfma_f32_16x16x32_bf16(af, bfm[j], acc[j], 0, 0, 0);
  }

#pragma unroll
  for (int j = 0; j < 4; j++) {
    const int nn = tn * 128 + qn + j * 16 + ln;
    const float bias = bfv[nn];
#pragma unroll
    for (int r = 0; r < 4; r++) {
      const int rr = rr0 + qm + quad * 4 + r;
      out[(size_t)rr * 512 + nn] = acc[j][r] + bias;
    }
  }
}

// ---------------------------------------------------------------------------
extern "C" void kernel_launch(void* const* d_in, const int* in_sizes, int n_in,
                              void* d_out, int out_size, void* d_ws, size_t ws_size,
                              hipStream_t stream) {
  const float* q   = (const float*)d_in[0];
  const float* k   = (const float*)d_in[1];
  const float* v   = (const float*)d_in[2];
  const float* pe  = (const float*)d_in[3];
  const float* Wq  = (const float*)d_in[4];
  const float* bq  = (const float*)d_in[5];
  const float* Wp  = (const float*)d_in[6];
  const float* Wf  = (const float*)d_in[7];
  const float* bfv = (const float*)d_in[8];
  const float* ub  = (const float*)d_in[9];
  const float* vb  = (const float*)d_in[10];

  bf16* ws  = (bf16*)d_ws;
  bf16* qh  = ws;                  // qh first: t+1 tail reads land in kh (finite, unused)
  bf16* kh  = qh + 2097152;
  bf16* vT  = kh + 2097152;
  bf16* phx = vT + 2097152;
  bf16* WqT = phx + 4194304;
  bf16* WpT = WqT + 262144;
  bf16* WfT = WpT + 262144;
  bf16* ctx = WfT + 262144;

  prep_kernel<<<192, 256, 0, stream>>>(Wq, Wp, Wf, WqT, WpT, WfT);
  proj_gemm<<<512, 256, 0, stream>>>(q, k, v, pe, WqT, WpT, bq, qh, kh, vT, phx);
  attn_kernel<<<1024, 256, 0, stream>>>(qh, kh, vT, phx, ub, vb, ctx);
  out_gemm<<<512, 256, 0, stream>>>(ctx, WfT, bfv, (float*)d_out);
}